// Round 9
// baseline (193.628 us; speedup 1.0000x reference)
//
#include <hip/hip_runtime.h>

namespace {

constexpr int BD = 2;
constexpr int DD = 160, HH = 192, WW = 224;
constexpr float INV_WIN = 1.0f / 729.0f;
constexpr float EPSV = 1e-5f;

constexpr int TH = 16, TW = 16;          // output tile (H x W)
constexpr int DC = 16;                   // output planes per d-chunk
constexpr int NREAL = DC + 8;            // 24 plane steps = 12 pairs
constexpr int NPAIR = NREAL / 2;         // 12; superstep loop runs 13 (pipelined)
constexpr int NCH = DD / DC;             // 10
constexpr int GX = WW / TW;              // 14
constexpr int GY = HH / TH;              // 12
constexpr int GZ = BD * NCH;             // 20
constexpr int NBLK = GX * GY * GZ;       // 3360
constexpr int NXCD = 8;
constexpr int CPX = NBLK / NXCD;         // 420 (3360 % 8 == 0 -> bijective swizzle)
constexpr double NTOT = (double)BD * DD * HH * WW;

// srow: [buf][plane][field][w*28 + row], rows 0..23 contiguous (pad 28).
// SR_FS=452 (f-shift /4=113==1 mod 8), SR_PL=2280 (==8 mod 32). Audited:
// S2 b32 scatter 2/bank (b32 floor; t-stride 28 dw is ds_write2-reachable);
// S3 b128 reads uniform /quad.
constexpr int SR_FS = 452;
constexpr int SR_PL = 2280;
// scol (R9 RELAYOUT): [w][plane][field][oh] -> scolF[w*SC_W + p*SC_P +
// f*SC_F + oh], oh 0..15 (pad 4). Purpose: S4's 10 reads/thread share ONE
// base VGPR with imm offsets {0,20,...,180} dw — ALL within ds_read2_b32's
// 255-dw immediate reach, so the DS-combiner merges them into 5x read2
// (old field stride 324 dw was unreachable -> 10 unmerged b32).
// Bank audit: S3 b128 write quad = (3*wl3 + p3 + 5*f3 + t) mod 8, 3 coprime
// 8 -> uniform /quad; S4 read bank = (12*ow + oh) mod 32 -> exactly 2/bank
// (b32 floor); read2's +20dw second word shifts all lanes equally.
constexpr int SC_F = 20;                 // field stride (16 oh + pad 4)
constexpr int SC_P = 100;                // plane stride (5 fields)
constexpr int SC_W = 204;                // w stride (2*SC_P + pad 4; 204/4=51 odd quads)
constexpr int SC_SZ = 16 * SC_W;         // 3264 floats = 13056 B

} // namespace

// R8 structure (best measured: fused 101.5 us, total 193.5) + scol relayout
// for S4 read2-merge. Session model (9 measurements): dur x VALUBusy ~= 46 us
// (fixed VALU-issue work); per-CU serial terms ~46 us VALU || ~67 us LDS-pipe
// issue (130 ds-wave-instrs/ss-block). R8 (XCD swizzle on exact R0) removed
// the HBM-latency stall: 115 -> 101.5 us. This round attacks the LDS-issue
// term: S4 40 -> 20 wave-instrs/ss-block via read2 pairing (~10% of the
// LDS-pipe floor). Everything else byte-identical to R8.
// DO NOT (measured): min-waves launch_bounds (R1 spill 3x); single-plane
// epochs (R2 1.65x); one-shot grid / rolled loop (R3 1.6x); 512-thr blocks
// (R4); DC>16 (R5 VGPR 128); 5-blk residency squeeze (R6 flat); 1-barrier
// merge (R7 flat). Transposes are width-optimal — do not flip.
__global__ __launch_bounds__(256)
void ncc_fused(const float* __restrict__ x, const float* __restrict__ y,
               float* __restrict__ bsum) {
  const int tid = threadIdx.x;

  // XCD-chunked swizzle: halo re-reads hit same-XCD L2 (~200cy) not HBM
  // (~900cy). Proven: FETCH 348->75 MB, fused 115->101.5 on this structure.
  const int lid = (int)blockIdx.x;
  const int nl  = (lid & (NXCD - 1)) * CPX + (lid >> 3);
  const int zb  = nl / (GX * GY);
  const int rem = nl - zb * (GX * GY);
  const int by  = rem / GX;
  const int bx  = rem - by * GX;

  const int w0 = bx * TW;
  const int h0 = by * TH;
  const int b  = zb / NCH;
  const int d0 = (zb - b * NCH) * DC;

  __shared__ __align__(16) float srowF[2][2 * SR_PL];  // 36480 B (pair dbuf)
  __shared__ __align__(16) float scolF[SC_SZ];         // 13056 B
  __shared__ float swsum[4];

  // ---- S2 roles: tids 0..191 = 2 planes x 24 rows x 4 col-segments,
  // 12-wide register window -> 4 sliding 9-tap W-sums x 5 fields.
  const bool s2a = tid < 192;
  const int p2  = tid / 96;
  const int t96 = tid - 96 * p2;
  const int r2  = t96 >> 2;            // input row 0..23
  const int seg = tid & 3;
  const int gh  = h0 - 4 + r2;
  const int gw0 = w0 - 4 + seg * 4;    // 16B aligned
  const bool hok = (unsigned)gh < (unsigned)HH;
  const bool fastw = (gw0 >= 0) && (gw0 + 11 < WW);
  const unsigned plane = (unsigned)HH * WW;

  auto prefetch = [&](int s, float4* vx, float4* vy) {
    const int din = d0 - 4 + s;
    const float4 z = make_float4(0.f, 0.f, 0.f, 0.f);
    vx[0] = vx[1] = vx[2] = z;
    vy[0] = vy[1] = vy[2] = z;
    if (s2a && hok && (s < NREAL) && (din >= 0) && (din < DD)) {
      const unsigned rb = ((unsigned)b * DD + (unsigned)din) * plane + (unsigned)gh * WW;
      if (fastw) {
        const float4* px = (const float4*)(x + rb + gw0);
        const float4* py = (const float4*)(y + rb + gw0);
        vx[0] = px[0]; vx[1] = px[1]; vx[2] = px[2];
        vy[0] = py[0]; vy[1] = py[1]; vy[2] = py[2];
      } else {
        float* fx = (float*)vx;
        float* fy = (float*)vy;
#pragma unroll
        for (int e = 0; e < 12; ++e) {
          const int gw = gw0 + e;
          if ((unsigned)gw < (unsigned)WW) {
            fx[e] = x[rb + gw];
            fy[e] = y[rb + gw];
          }
        }
      }
    }
  };

  // ---- S3 roles: tids 96..255 = 2 planes x 5 fields x 16 w (wave balance:
  // wave0 S2-only, wave3 S3-only, waves1-2 mixed).
  const int t3  = tid - 96;
  const int p3  = t3 / 80;
  const int r3  = t3 - 80 * p3;
  const int f3  = r3 >> 4;
  const int wl3 = r3 & 15;

  const int ow = tid & 15;
  const int oh = tid >> 4;

  // D-ring: 9 slots x 5 fields; slot indices static after full unroll.
  float rg0[9], rg1[9], rg2[9], rg3[9], rg4[9];
#pragma unroll
  for (int k = 0; k < 9; ++k) { rg0[k]=0.f; rg1[k]=0.f; rg2[k]=0.f; rg3[k]=0.f; rg4[k]=0.f; }
  float a0=0.f, a1=0.f, a2=0.f, a3=0.f, a4=0.f;
  float lsum = 0.0f;

  float4 px4[3], py4[3];
  prefetch(p2, px4, py4);               // pair 0

  // Pipelined supersteps: S2 stages pair ss; S3/S4 consume pair ss-1.
#pragma unroll
  for (int ss = 0; ss <= NPAIR; ++ss) {
    // prefetch pair ss+1 (consumed by S2 next superstep)
    float4 nx4[3], ny4[3];
    if (ss + 1 < NPAIR) prefetch(2 * (ss + 1) + p2, nx4, ny4);

    // ---- S2 (pair ss): W-sums -> srow[ss&1]. Independent of S3 below.
    if (ss < NPAIR && s2a) {
      float xv[12], yv[12];
#pragma unroll
      for (int k = 0; k < 3; ++k) {
        *(float4*)&xv[4 * k] = px4[k];
        *(float4*)&yv[4 * k] = py4[k];
      }
      float s0=0.f, s1=0.f, s2=0.f, s3=0.f, s4=0.f;
#pragma unroll
      for (int k = 0; k < 9; ++k) {
        s0 += xv[k]; s1 += yv[k];
        s2 = fmaf(xv[k], xv[k], s2);
        s3 = fmaf(yv[k], yv[k], s3);
        s4 = fmaf(xv[k], yv[k], s4);
      }
      float* wb = &srowF[ss & 1][p2 * SR_PL + (seg * 4) * 28 + r2];
      wb[0 * SR_FS] = s0; wb[1 * SR_FS] = s1; wb[2 * SR_FS] = s2;
      wb[3 * SR_FS] = s3; wb[4 * SR_FS] = s4;
#pragma unroll
      for (int t = 1; t < 4; ++t) {
        const float xn = xv[8 + t], xo = xv[t - 1];
        const float yn = yv[8 + t], yo = yv[t - 1];
        s0 += xn - xo;
        s1 += yn - yo;
        s2 += fmaf(xn, xn, -(xo * xo));
        s3 += fmaf(yn, yn, -(yo * yo));
        s4 += fmaf(xn, yn, -(xo * yo));
        float* wt = wb + t * 28;
        wt[0 * SR_FS] = s0; wt[1 * SR_FS] = s1; wt[2 * SR_FS] = s2;
        wt[3 * SR_FS] = s3; wt[4 * SR_FS] = s4;
      }
    }

    // ---- S3 (pair ss-1): H-sums from srow[(ss-1)&1] -> scol.
    // No barrier needed vs S2: different srow buffer (written last superstep,
    // separated by barrier E(ss-1)).
    if (ss >= 1 && tid >= 96) {
      const float* rp = &srowF[(ss - 1) & 1][p3 * SR_PL + f3 * SR_FS + wl3 * 28];
      float rv[24];
#pragma unroll
      for (int t = 0; t < 6; ++t) *(float4*)&rv[4 * t] = *(const float4*)&rp[4 * t];
      float acc = rv[0];
#pragma unroll
      for (int t = 1; t < 9; ++t) acc += rv[t];
      float ov[16];
      ov[0] = acc;
#pragma unroll
      for (int o = 1; o < 16; ++o) { acc += rv[o + 8] - rv[o - 1]; ov[o] = acc; }
      // R9: [w][plane][field][oh] layout; still 4x contiguous b128 (base
      // dword wl3*204 + p3*100 + f3*20 is 0 mod 4 -> 16B aligned).
      float* cp = &scolF[wl3 * SC_W + p3 * SC_P + f3 * SC_F];
#pragma unroll
      for (int t = 0; t < 4; ++t)
        *(float4*)&cp[4 * t] = make_float4(ov[4*t], ov[4*t+1], ov[4*t+2], ov[4*t+3]);
    }
    __syncthreads();   // C: scol visible (also orders S2 writes vs next S3)

    // ---- S4 (pair ss-1): ring update + emit (all 256 threads).
    // R9: all 10 loads share base &scolF[ow*SC_W+oh], imms {0,20,..,180} dw
    // -> DS-combiner emits 5x ds_read2_b32 (was 10x unmergeable b32).
    if (ss >= 1) {
      const int sA  = 2 * (ss - 1);
      const int sB  = sA + 1;
      const int slA = sA % 9;
      const int slB = sB % 9;
      const float* c = &scolF[ow * SC_W + oh];
      const float gA0 = c[0*SC_F],          gA1 = c[1*SC_F],          gA2 = c[2*SC_F],
                  gA3 = c[3*SC_F],          gA4 = c[4*SC_F];
      const float gB0 = c[SC_P + 0*SC_F],   gB1 = c[SC_P + 1*SC_F],   gB2 = c[SC_P + 2*SC_F],
                  gB3 = c[SC_P + 3*SC_F],   gB4 = c[SC_P + 4*SC_F];

      a0 += gA0 - rg0[slA]; rg0[slA] = gA0;
      a1 += gA1 - rg1[slA]; rg1[slA] = gA1;
      a2 += gA2 - rg2[slA]; rg2[slA] = gA2;
      a3 += gA3 - rg3[slA]; rg3[slA] = gA3;
      a4 += gA4 - rg4[slA]; rg4[slA] = gA4;
      if (sA >= 8) {
        const float cross = fmaf(-a0 * INV_WIN, a1, a4);
        const float iv = fmaxf(fmaf(-a0 * INV_WIN, a0, a2), EPSV);
        const float jv = fmaxf(fmaf(-a1 * INV_WIN, a1, a3), EPSV);
        lsum += (cross * cross) / (iv * jv);
      }
      a0 += gB0 - rg0[slB]; rg0[slB] = gB0;
      a1 += gB1 - rg1[slB]; rg1[slB] = gB1;
      a2 += gB2 - rg2[slB]; rg2[slB] = gB2;
      a3 += gB3 - rg3[slB]; rg3[slB] = gB3;
      a4 += gB4 - rg4[slB]; rg4[slB] = gB4;
      if (sB >= 8) {
        const float cross = fmaf(-a0 * INV_WIN, a1, a4);
        const float iv = fmaxf(fmaf(-a0 * INV_WIN, a0, a2), EPSV);
        const float jv = fmaxf(fmaf(-a1 * INV_WIN, a1, a3), EPSV);
        lsum += (cross * cross) / (iv * jv);
      }
    }
    __syncthreads();   // E: S4 scol-reads done before S3(ss+1) overwrites;
                       //    S2(ss) srow writes visible to S3(ss+1).
    if (ss + 1 < NPAIR) {
#pragma unroll
      for (int k = 0; k < 3; ++k) { px4[k] = nx4[k]; py4[k] = ny4[k]; }
    }
  }

  // ---- block reduction
#pragma unroll
  for (int off = 32; off > 0; off >>= 1) lsum += __shfl_down(lsum, off);
  if ((tid & 63) == 0) swsum[tid >> 6] = lsum;
  __syncthreads();
  if (tid == 0) bsum[nl] = swsum[0] + swsum[1] + swsum[2] + swsum[3];
}

__global__ __launch_bounds__(256)
void ncc_finalize(const float* __restrict__ bsum, float* __restrict__ out) {
  double s = 0.0;
  for (int i = threadIdx.x; i < NBLK; i += 256) s += (double)bsum[i];
#pragma unroll
  for (int off = 32; off > 0; off >>= 1) s += __shfl_down(s, off);
  __shared__ double sh[4];
  if ((threadIdx.x & 63) == 0) sh[threadIdx.x >> 6] = s;
  __syncthreads();
  if (threadIdx.x == 0)
    out[0] = (float)(-(sh[0] + sh[1] + sh[2] + sh[3]) / NTOT);
}

extern "C" void kernel_launch(void* const* d_in, const int* in_sizes, int n_in,
                              void* d_out, int out_size, void* d_ws, size_t ws_size,
                              hipStream_t stream) {
  const float* x = (const float*)d_in[0];
  const float* y = (const float*)d_in[1];
  float* bsum = (float*)d_ws;          // 3360 floats, fully rewritten every call
  float* out  = (float*)d_out;

  dim3 grid(NBLK);
  ncc_fused<<<grid, dim3(256), 0, stream>>>(x, y, bsum);
  ncc_finalize<<<1, dim3(256), 0, stream>>>(bsum, out);
}